// Round 7
// baseline (419.556 us; speedup 1.0000x reference)
//
#include <hip/hip_runtime.h>
#include <hip/hip_bf16.h>

// GptOssMoEExperts on MI355X — round 7.
// Router is a no-op (sum of softmax over top-k == 1):
//   out = (gate * silu(up)) @ down_w^T + down_b,  [gate|up] = hs @ gate_up_w^T + b.
//
// Round-6 regression diagnosis: A-fragment ds_reads were INSIDE the MFMA loop
// (read af[m] -> 6 MFMA -> read af[m+1]), exposing ~90 cyc LDS latency per
// m-group that 2 waves/SIMD can't hide. Round 7 keeps round-6 geometry
// (BM=256 x BN=192/mat, 2Mx4N waves, 128x96 wave tile, ring-3, vmcnt(5))
// and hoists ALL fragment reads ahead of the MFMA cluster in two groups:
// {afA,gf,uf} -> stage(t+2) -> {afB} -> 48 MFMAs.  gemm2/convert3 unchanged.

typedef __bf16 bf16_t;
typedef bf16_t bf16x8 __attribute__((ext_vector_type(8)));
typedef bf16_t bf16x4 __attribute__((ext_vector_type(4)));
typedef float f32x4 __attribute__((ext_vector_type(4)));

#define SEQ   4096
#define HID   2880
#define INTER 2880
#define BK    32
#define NT    90   // 2880 / 32, same K depth for both GEMMs

#define GLD16(srcp, ldsp)                                                     \
  __builtin_amdgcn_global_load_lds(                                           \
      (const __attribute__((address_space(1))) unsigned int*)(srcp),          \
      (__attribute__((address_space(3))) unsigned int*)(ldsp), 16, 0, 0)

#define BARRIER()                                                             \
  do {                                                                        \
    __builtin_amdgcn_sched_barrier(0);                                        \
    __builtin_amdgcn_s_barrier();                                             \
    __builtin_amdgcn_sched_barrier(0);                                        \
  } while (0)

#define VMCNT(n) asm volatile("s_waitcnt vmcnt(" #n ")" ::: "memory")

// Byte offset inside a [rows][32 bf16] LDS tile, row-pair XOR swizzle.
// slot = ((row&1)<<2 | chunk) ^ ((row>>1)&7); byte = (row>>1)*128 + slot*16.
// Measured 0 bank conflicts (rounds 2/5/6). swz(row+16,c) = swz(row,c)+1024.
__device__ __forceinline__ int swz(int row, int chunk) {
  int slot = (((row & 1) << 2) | chunk) ^ ((row >> 1) & 7);
  return ((row >> 1) << 7) + (slot << 4);
}

// gemm2's stage helper: NLOADS*512 16B-chunks, linear LDS dest,
// inverse-swizzled global source (rule #21).
template <int NLOADS>
__device__ __forceinline__ void stage(const bf16_t* __restrict__ src,
                                      int row_base, int row_max, int k0,
                                      char* ldsb, int tid) {
#pragma unroll
  for (int i = 0; i < NLOADS; ++i) {
    const int c = i * 512 + tid;
    const int rp = c >> 3;
    const int slot = c & 7;
    const int v = slot ^ (rp & 7);
    int srow = rp * 2 + (v >> 2);
    if (srow > row_max) srow = row_max;
    const bf16_t* g = src + (size_t)(row_base + srow) * HID + k0 + (v & 3) * 8;
    GLD16(g, ldsb + (size_t)(i * 512 + (tid & ~63)) * 16);
  }
}

// ---------------------------------------------------------------------------
// K1: fp32 -> bf16 conversion of hs, gate_up_w, down_w (contiguous in ws)
// ---------------------------------------------------------------------------
__global__ __launch_bounds__(256) void convert3(const float* __restrict__ a,
                                                const float* __restrict__ b,
                                                const float* __restrict__ c,
                                                bf16_t* __restrict__ o) {
  constexpr size_t na = (size_t)SEQ * HID;
  constexpr size_t nb = (size_t)(2 * INTER) * HID;
  constexpr size_t nc = (size_t)HID * INTER;
  size_t i = ((size_t)blockIdx.x * 256 + threadIdx.x) * 4;
  if (i >= na + nb + nc) return;
  const float* src;
  if (i < na)            src = a + i;
  else if (i < na + nb)  src = b + (i - na);
  else                   src = c + (i - na - nb);
  float4 v = *(const float4*)src;
  bf16x4 r = {(bf16_t)v.x, (bf16_t)v.y, (bf16_t)v.z, (bf16_t)v.w};
  *(bf16x4*)(o + i) = r;
}

// ---------------------------------------------------------------------------
// K2: fused gate/up GEMM + silu.  BM=256, BN=192 per mat, 8 waves (2M x 4N),
// wave tile 128 x (48 gate + 48 up).  LDS slot = A 16K + G 12K + U 12K = 40K,
// ring-3 = 120 KiB.  Per thread per K-tile: 5 gload_lds.  Per wave per
// K-tile: 14 ds_read_b128 (ALL hoisted before MFMA), 48 MFMA, vmcnt(5).
// ---------------------------------------------------------------------------
__global__ __launch_bounds__(512, 2) void gemm1(const bf16_t* __restrict__ A,
                                                const bf16_t* __restrict__ GW,
                                                const float* __restrict__ bias,
                                                bf16_t* __restrict__ X) {
  __shared__ char sm[3 * 40960];
  const bf16_t* UW = GW + (size_t)INTER * HID;  // up half of gate_up_w

  const int tid = threadIdx.x;
  const int w = tid >> 6, l = tid & 63;
  const int wm = w >> 2, wn = w & 3;            // 2M x 4N wave grid
  const int l15 = l & 15, l4 = l >> 4;
  const int row0 = blockIdx.x * 256;
  const int col0 = blockIdx.y * 192;

  // --- staging streams: 5 per thread (A c=tid,512+tid; G/U c=i*512+tid) ---
  const bf16_t* pS[5];
  int dL[5];
#pragma unroll
  for (int i = 0; i < 2; ++i) {                 // A: 1024 chunks, rows 0..255
    const int c = i * 512 + tid;
    const int rp = c >> 3, sl = c & 7, v = sl ^ (rp & 7);
    const int srow = rp * 2 + (v >> 2);
    pS[i] = A + (size_t)(row0 + srow) * HID + (v & 3) * 8;
    dL[i] = (i * 512 + (tid & ~63)) * 16;
  }
#pragma unroll
  for (int i = 0; i < 3; ++i) {                 // G(768 chunks) then U(768)
    const int c = i * 512 + tid;
    const int cc = c < 768 ? c : c - 768;
    const bf16_t* const base = c < 768 ? GW : UW;
    const int rp = cc >> 3, sl = cc & 7, v = sl ^ (rp & 7);
    const int srow = rp * 2 + (v >> 2);         // 0..191
    pS[2 + i] = base + (size_t)(col0 + srow) * HID + (v & 3) * 8;
    dL[2 + i] = 16384 + (i * 512 + (tid & ~63)) * 16;
  }

#define G1_STAGE(T, sb)                                                       \
  do {                                                                        \
    const int kk_ = (T) * BK;                                                 \
    _Pragma("unroll") for (int i_ = 0; i_ < 5; ++i_)                          \
      GLD16(pS[i_] + kk_, (sb) + dL[i_]);                                     \
  } while (0)

  // --- LDS read bases (A at 0, G at 16384, U at 28672); +1024 per 16 rows ---
  const int rdA = swz(wm * 128 + l15, l4);
  const int rdG = 16384 + swz(wn * 48 + l15, l4);
  const int rdU = rdG + 12288;

  f32x4 accg[8][3], accu[8][3];
#pragma unroll
  for (int m = 0; m < 8; ++m)
#pragma unroll
    for (int n = 0; n < 3; ++n) {
      accg[m][n] = (f32x4){0.f, 0.f, 0.f, 0.f};
      accu[m][n] = (f32x4){0.f, 0.f, 0.f, 0.f};
    }

  char* s0 = sm;
  char* s1 = sm + 40960;
  char* s2 = sm + 81920;

  // Prologue: stage tiles 0,1; wait tile 0 landed (5 of 10 retired).
  G1_STAGE(0, s0);
  G1_STAGE(1, s1);
  VMCNT(5);
  BARRIER();

#pragma unroll 1
  for (int t = 0; t < NT; ++t) {
    // Group 1: first half of A frags + all B frags (10 ds_read_b128).
    bf16x8 afA[4], afB[4], gf[3], uf[3];
#pragma unroll
    for (int m = 0; m < 4; ++m) afA[m] = *(const bf16x8*)(s0 + rdA + m * 1024);
#pragma unroll
    for (int n = 0; n < 3; ++n) {
      gf[n] = *(const bf16x8*)(s0 + rdG + n * 1024);
      uf[n] = *(const bf16x8*)(s0 + rdU + n * 1024);
    }
    // Stage t+2 (vm domain; does not block the lgkm reads).
    if (t + 2 < NT) G1_STAGE(t + 2, s2);
    // Group 2: second half of A frags — latency covered by the first
    // 24-MFMA cluster (progressive lgkmcnt).
#pragma unroll
    for (int m = 0; m < 4; ++m) afB[m] = *(const bf16x8*)(s0 + rdA + (m + 4) * 1024);

    __builtin_amdgcn_s_setprio(1);
#pragma unroll
    for (int m = 0; m < 4; ++m)
#pragma unroll
      for (int n = 0; n < 3; ++n) {
        accg[m][n] = __builtin_amdgcn_mfma_f32_16x16x32_bf16(afA[m], gf[n], accg[m][n], 0, 0, 0);
        accu[m][n] = __builtin_amdgcn_mfma_f32_16x16x32_bf16(afA[m], uf[n], accu[m][n], 0, 0, 0);
      }
#pragma unroll
    for (int m = 0; m < 4; ++m)
#pragma unroll
      for (int n = 0; n < 3; ++n) {
        accg[m + 4][n] = __builtin_amdgcn_mfma_f32_16x16x32_bf16(afB[m], gf[n], accg[m + 4][n], 0, 0, 0);
        accu[m + 4][n] = __builtin_amdgcn_mfma_f32_16x16x32_bf16(afB[m], uf[n], accu[m + 4][n], 0, 0, 0);
      }
    __builtin_amdgcn_s_setprio(0);
    // Boundary: tile t+1 must be resident; keep t+2's 5 loads in flight.
    if (t < NT - 2)       { VMCNT(5); }
    else if (t == NT - 2) { VMCNT(0); }
    BARRIER();
    char* const sx = s0; s0 = s1; s1 = s2; s2 = sx;  // ring-3 rotate
  }

  // Epilogue: x = (gate+bg) * silu(up+bu).  C/D: col=lane&15, row=(lane>>4)*4+j.
#pragma unroll
  for (int n = 0; n < 3; ++n) {
    const int col = col0 + wn * 48 + n * 16 + l15;
    const float bg = bias[col];
    const float bu = bias[INTER + col];
#pragma unroll
    for (int m = 0; m < 8; ++m) {
      const int r = row0 + wm * 128 + m * 16 + l4 * 4;
#pragma unroll
      for (int j = 0; j < 4; ++j) {
        const float g = accg[m][n][j] + bg;
        const float u = accu[m][n][j] + bu;
        X[(size_t)(r + j) * INTER + col] = (bf16_t)(g * (u / (1.f + __expf(-u))));
      }
    }
  }
#undef G1_STAGE
}

// ---------------------------------------------------------------------------
// K3: out = x @ down_w^T + down_b.  UNCHANGED (round-5 structure, isolates
// gemm1's delta).  BM=256, BN=192, 8 waves (4M x 2N), wave 64x96, ring-4,
// counted vmcnt(8).
// ---------------------------------------------------------------------------
__global__ __launch_bounds__(512, 2) void gemm2(const bf16_t* __restrict__ A,
                                                const bf16_t* __restrict__ B,
                                                const float* __restrict__ bias,
                                                float* __restrict__ out) {
  __shared__ char sm[4 * 32768];
  const int tid = threadIdx.x;
  const int w = tid >> 6, l = tid & 63;
  const int wm = w >> 1, wn = w & 1;
  const int l15 = l & 15, l4 = l >> 4;
  const int row0 = blockIdx.x * 256;
  const int col0 = blockIdx.y * 192;

  int rdA[4], rdB[6];
#pragma unroll
  for (int m = 0; m < 4; ++m) rdA[m] = swz(wm * 64 + m * 16 + l15, l4);
#pragma unroll
  for (int n = 0; n < 6; ++n) rdB[n] = 16384 + swz(wn * 96 + n * 16 + l15, l4);

  f32x4 acc[4][6];
#pragma unroll
  for (int m = 0; m < 4; ++m)
#pragma unroll
    for (int n = 0; n < 6; ++n) acc[m][n] = (f32x4){0.f, 0.f, 0.f, 0.f};

  for (int t = 0; t < 3; ++t) {
    char* s = sm + t * 32768;
    stage<2>(A, row0, 255, t * BK, s, tid);
    stage<2>(B, col0, 191, t * BK, s + 16384, tid);
  }
  VMCNT(8);
  BARRIER();

#pragma unroll 1
  for (int t = 0; t < NT; ++t) {
    char* sa = sm + (t & 3) * 32768;
    char* ss = sm + ((t + 3) & 3) * 32768;

    bf16x8 af[4], bfr[6];
#pragma unroll
    for (int m = 0; m < 4; ++m) af[m] = *(const bf16x8*)(sa + rdA[m]);
#pragma unroll
    for (int n = 0; n < 6; ++n) bfr[n] = *(const bf16x8*)(sa + rdB[n]);
    if (t + 3 < NT) {
      stage<2>(A, row0, 255, (t + 3) * BK, ss, tid);
      stage<2>(B, col0, 191, (t + 3) * BK, ss + 16384, tid);
    }
    __builtin_amdgcn_s_setprio(1);
#pragma unroll
    for (int m = 0; m < 4; ++m)
#pragma unroll
      for (int n = 0; n < 6; ++n)
        acc[m][n] = __builtin_amdgcn_mfma_f32_16x16x32_bf16(af[m], bfr[n], acc[m][n], 0, 0, 0);
    __builtin_amdgcn_s_setprio(0);
    if (t < NT - 3)       { VMCNT(8); }
    else if (t == NT - 3) { VMCNT(4); }
    else if (t == NT - 2) { VMCNT(0); }
    BARRIER();
  }

#pragma unroll
  for (int n = 0; n < 6; ++n) {
    const int col = col0 + wn * 96 + n * 16 + l15;
    const float bb = bias[col];
#pragma unroll
    for (int m = 0; m < 4; ++m) {
      const int r = row0 + wm * 64 + m * 16 + l4 * 4;
#pragma unroll
      for (int j = 0; j < 4; ++j)
        out[(size_t)(r + j) * HID + col] = acc[m][n][j] + bb;
    }
  }
}

// ---------------------------------------------------------------------------
extern "C" void kernel_launch(void* const* d_in, const int* in_sizes, int n_in,
                              void* d_out, int out_size, void* d_ws, size_t ws_size,
                              hipStream_t stream) {
  (void)in_sizes; (void)n_in; (void)out_size; (void)ws_size;

  const float* hs  = (const float*)d_in[0];  // (4096, 2880)
  // d_in[1] router_w, d_in[2] router_b: unused — sum(softmax(topk)) == 1.
  const float* guw = (const float*)d_in[3];  // (5760, 2880)
  const float* gub = (const float*)d_in[4];  // (5760,)
  const float* dww = (const float*)d_in[5];  // (2880, 2880)
  const float* dwb = (const float*)d_in[6];  // (2880,)
  float* out = (float*)d_out;                // (4096, 2880)

  constexpr size_t n_hs  = (size_t)SEQ * HID;
  constexpr size_t n_guw = (size_t)(2 * INTER) * HID;
  constexpr size_t n_dww = (size_t)HID * INTER;

  bf16_t* ws   = (bf16_t*)d_ws;
  bf16_t* hsb  = ws;
  bf16_t* guwb = hsb + n_hs;
  bf16_t* dwwb = guwb + n_guw;
  bf16_t* xb   = dwwb + n_dww;  // (4096, 2880) bf16

  const size_t total4 = (n_hs + n_guw + n_dww) / 4;
  const int cgrid = (int)((total4 + 255) / 256);
  convert3<<<cgrid, 256, 0, stream>>>(hs, guw, dww, ws);

  dim3 g1(SEQ / 256, INTER / 192);  // 16 x 15 = 240 blocks, single round
  gemm1<<<g1, 512, 0, stream>>>(hsb, guwb, gub, xb);

  dim3 g2(SEQ / 256, HID / 192);    // 16 x 15 = 240 blocks
  gemm2<<<g2, 512, 0, stream>>>(xb, dwwb, dwb, out);
}

// Round 9
// 412.581 us; speedup vs baseline: 1.0169x; 1.0169x over previous
//
#include <hip/hip_runtime.h>
#include <hip/hip_bf16.h>

// GptOssMoEExperts on MI355X — round 9 (round-8 resubmit: container infra
// failure, kernel never ran).
// Router is a no-op (sum of softmax over top-k == 1):
//   out = (gate * silu(up)) @ down_w^T + down_b,  [gate|up] = hs @ gate_up_w^T + b.
//
// Rounds 6/7 falsified the 128-row-wave geometry (48-frag acc -> scratch
// spills, WRITE_SIZE 23->46->60 MB). This round reverts to round-5 economics
// (wave tile 64x96, 24 frags) but HALVES the block: BM=128, 256 threads,
// 4 waves (2Mx2N), LDS slot 20K x ring-4 = 80K -> exactly 2 independent
// blocks per CU. Blocks don't share barriers, so one block's MFMA hides the
// other's barrier/load stalls (m97 mechanism). Per-CU LDS read volume is
// unchanged (80 ds_read_b128 per K-tile). Counted vmcnt ladder 10/5/0
// (5 loads/thread/tile, prefetch 3). Bijective XCD swizzle groups blocks
// sharing an A-panel on one XCD's L2.

typedef __bf16 bf16_t;
typedef bf16_t bf16x8 __attribute__((ext_vector_type(8)));
typedef bf16_t bf16x4 __attribute__((ext_vector_type(4)));
typedef float f32x4 __attribute__((ext_vector_type(4)));

#define SEQ   4096
#define HID   2880
#define INTER 2880
#define BK    32
#define NT    90   // 2880 / 32, same K depth for both GEMMs

#define GLD16(srcp, ldsp)                                                     \
  __builtin_amdgcn_global_load_lds(                                           \
      (const __attribute__((address_space(1))) unsigned int*)(srcp),          \
      (__attribute__((address_space(3))) unsigned int*)(ldsp), 16, 0, 0)

#define BARRIER()                                                             \
  do {                                                                        \
    __builtin_amdgcn_sched_barrier(0);                                        \
    __builtin_amdgcn_s_barrier();                                             \
    __builtin_amdgcn_sched_barrier(0);                                        \
  } while (0)

#define VMCNT(n) asm volatile("s_waitcnt vmcnt(" #n ")" ::: "memory")

// Byte offset inside a [rows][32 bf16] LDS tile, row-pair XOR swizzle.
// slot = ((row&1)<<2 | chunk) ^ ((row>>1)&7); byte = (row>>1)*128 + slot*16.
// Measured 0 bank conflicts (rounds 2/5/6/7). swz(row+16,c) = swz(row,c)+1024.
__device__ __forceinline__ int swz(int row, int chunk) {
  int slot = (((row & 1) << 2) | chunk) ^ ((row >> 1) & 7);
  return ((row >> 1) << 7) + (slot << 4);
}

// ---------------------------------------------------------------------------
// K1: fp32 -> bf16 conversion of hs, gate_up_w, down_w (contiguous in ws).
// 220 MB at ~6.3 TB/s -> ~35 us (measured at HBM ceiling).
// ---------------------------------------------------------------------------
__global__ __launch_bounds__(256) void convert3(const float* __restrict__ a,
                                                const float* __restrict__ b,
                                                const float* __restrict__ c,
                                                bf16_t* __restrict__ o) {
  constexpr size_t na = (size_t)SEQ * HID;
  constexpr size_t nb = (size_t)(2 * INTER) * HID;
  constexpr size_t nc = (size_t)HID * INTER;
  size_t i = ((size_t)blockIdx.x * 256 + threadIdx.x) * 4;
  if (i >= na + nb + nc) return;
  const float* src;
  if (i < na)            src = a + i;
  else if (i < na + nb)  src = b + (i - na);
  else                   src = c + (i - na - nb);
  float4 v = *(const float4*)src;
  bf16x4 r = {(bf16_t)v.x, (bf16_t)v.y, (bf16_t)v.z, (bf16_t)v.w};
  *(bf16x4*)(o + i) = r;
}

// ---------------------------------------------------------------------------
// K2: fused gate/up GEMM + silu.  BM=128, gate 96 + up 96 cols per block,
// 4 waves (2M x 2N), wave tile 64 x (48+48), 24 acc frags (96 VGPR).
// LDS slot = A 8K + G 6K + U 6K = 20K, ring-4 = 80K -> 2 blocks/CU.
// Per thread per K-tile: 5 gload_lds (A 2, G/U 3).  Per wave: 10 ds_read_b128
// hoisted, 24 MFMA.  Counted vmcnt(10/5/0), prefetch 3.
// Grid: 32 x 30 = 960 blocks (1D, XCD-swizzled: 960 = 8 x 120).
// ---------------------------------------------------------------------------
__global__ __launch_bounds__(256, 2) void gemm1(const bf16_t* __restrict__ A,
                                                const bf16_t* __restrict__ GW,
                                                const float* __restrict__ bias,
                                                bf16_t* __restrict__ X) {
  __shared__ char sm[4 * 20480];
  const bf16_t* UW = GW + (size_t)INTER * HID;  // up half of gate_up_w

  // Bijective XCD swizzle (960 = 8 XCDs x 120) + col-major decompose so each
  // XCD's 120 consecutive blocks = 4 A-panels x 30 col-tiles (A hot in L2).
  const int wg = (blockIdx.x & 7) * 120 + (blockIdx.x >> 3);
  const int row0 = (wg / 30) * 128;
  const int col0 = (wg % 30) * 96;

  const int tid = threadIdx.x;
  const int w = tid >> 6, l = tid & 63;
  const int wm = w >> 1, wn = w & 1;            // 2M x 2N wave grid
  const int l15 = l & 15, l4 = l >> 4;

  // --- staging streams: 5 per thread (A: i<2, 512 chunks; G|U: i<3, 768) ---
  const bf16_t* pS[5];
  int dL[5];
#pragma unroll
  for (int i = 0; i < 2; ++i) {                 // A rows 0..127
    const int c = i * 256 + tid;
    const int rp = c >> 3, sl = c & 7, v = sl ^ (rp & 7);
    const int srow = rp * 2 + (v >> 2);
    pS[i] = A + (size_t)(row0 + srow) * HID + (v & 3) * 8;
    dL[i] = (i * 256 + (tid & ~63)) * 16;
  }
#pragma unroll
  for (int i = 0; i < 3; ++i) {                 // G (384 chunks) then U (384)
    const int c = i * 256 + tid;
    const int cc = c < 384 ? c : c - 384;
    const bf16_t* const base = c < 384 ? GW : UW;
    const int rp = cc >> 3, sl = cc & 7, v = sl ^ (rp & 7);
    const int srow = rp * 2 + (v >> 2);         // 0..95
    pS[2 + i] = base + (size_t)(col0 + srow) * HID + (v & 3) * 8;
    dL[2 + i] = 8192 + (i * 256 + (tid & ~63)) * 16;
  }

#define G1_STAGE(T, sb)                                                       \
  do {                                                                        \
    const int kk_ = (T) * BK;                                                 \
    _Pragma("unroll") for (int i_ = 0; i_ < 5; ++i_)                          \
      GLD16(pS[i_] + kk_, (sb) + dL[i_]);                                     \
  } while (0)

  // --- LDS read offsets (A at 0, G at 8192, U at 14336) ---
  int rdA[4], rdG[3], rdU[3];
#pragma unroll
  for (int m = 0; m < 4; ++m) rdA[m] = swz(wm * 64 + m * 16 + l15, l4);
#pragma unroll
  for (int n = 0; n < 3; ++n) {
    rdG[n] = 8192 + swz(wn * 48 + n * 16 + l15, l4);
    rdU[n] = 14336 + swz(wn * 48 + n * 16 + l15, l4);
  }

  f32x4 accg[4][3], accu[4][3];
#pragma unroll
  for (int m = 0; m < 4; ++m)
#pragma unroll
    for (int n = 0; n < 3; ++n) {
      accg[m][n] = (f32x4){0.f, 0.f, 0.f, 0.f};
      accu[m][n] = (f32x4){0.f, 0.f, 0.f, 0.f};
    }

  // Prologue: stage K-tiles 0,1,2 (15 loads); retire t0's 5, keep 10.
  G1_STAGE(0, sm);
  G1_STAGE(1, sm + 20480);
  G1_STAGE(2, sm + 40960);
  VMCNT(10);
  BARRIER();

#pragma unroll 1
  for (int t = 0; t < NT; ++t) {
    char* sa = sm + (t & 3) * 20480;
    char* ss = sm + ((t + 3) & 3) * 20480;

    bf16x8 af[4], gf[3], uf[3];
#pragma unroll
    for (int m = 0; m < 4; ++m) af[m] = *(const bf16x8*)(sa + rdA[m]);
#pragma unroll
    for (int n = 0; n < 3; ++n) {
      gf[n] = *(const bf16x8*)(sa + rdG[n]);
      uf[n] = *(const bf16x8*)(sa + rdU[n]);
    }
    if (t + 3 < NT) G1_STAGE(t + 3, ss);
    __builtin_amdgcn_s_setprio(1);
#pragma unroll
    for (int m = 0; m < 4; ++m)
#pragma unroll
      for (int n = 0; n < 3; ++n) {
        accg[m][n] = __builtin_amdgcn_mfma_f32_16x16x32_bf16(af[m], gf[n], accg[m][n], 0, 0, 0);
        accu[m][n] = __builtin_amdgcn_mfma_f32_16x16x32_bf16(af[m], uf[n], accu[m][n], 0, 0, 0);
      }
    __builtin_amdgcn_s_setprio(0);
    // Boundary: retire K-tile t+1's 5 loads, keep (t+2),(t+3) = 10 in flight.
    if (t < NT - 3)       { VMCNT(10); }
    else if (t == NT - 3) { VMCNT(5); }
    else if (t == NT - 2) { VMCNT(0); }
    BARRIER();
  }

  // Epilogue: x = (gate+bg) * silu(up+bu).  C/D: col=lane&15, row=(lane>>4)*4+j.
#pragma unroll
  for (int n = 0; n < 3; ++n) {
    const int col = col0 + wn * 48 + n * 16 + l15;
    const float bg = bias[col];
    const float bu = bias[INTER + col];
#pragma unroll
    for (int m = 0; m < 4; ++m) {
      const int r = row0 + wm * 64 + m * 16 + l4 * 4;
#pragma unroll
      for (int j = 0; j < 4; ++j) {
        const float g = accg[m][n][j] + bg;
        const float u = accu[m][n][j] + bu;
        X[(size_t)(r + j) * INTER + col] = (bf16_t)(g * (u / (1.f + __expf(-u))));
      }
    }
  }
#undef G1_STAGE
}

// ---------------------------------------------------------------------------
// K3: out = x @ down_w^T + down_b.  BM=128, BN=192, 4 waves (2M x 2N),
// wave tile 64x96, 24 acc frags.  LDS slot = A 8K + B 12K = 20K, ring-4 =
// 80K -> 2 blocks/CU.  5 loads/thread/tile, vmcnt(10/5/0), prefetch 3.
// Grid: 32 x 15 = 480 blocks (1D, XCD-swizzled: 480 = 8 x 60).
// ---------------------------------------------------------------------------
__global__ __launch_bounds__(256, 2) void gemm2(const bf16_t* __restrict__ A,
                                                const bf16_t* __restrict__ B,
                                                const float* __restrict__ bias,
                                                float* __restrict__ out) {
  __shared__ char sm[4 * 20480];

  const int wg = (blockIdx.x & 7) * 60 + (blockIdx.x >> 3);
  const int row0 = (wg / 15) * 128;
  const int col0 = (wg % 15) * 192;

  const int tid = threadIdx.x;
  const int w = tid >> 6, l = tid & 63;
  const int wm = w >> 1, wn = w & 1;
  const int l15 = l & 15, l4 = l >> 4;

  const bf16_t* pS[5];
  int dL[5];
#pragma unroll
  for (int i = 0; i < 2; ++i) {                 // A rows 0..127
    const int c = i * 256 + tid;
    const int rp = c >> 3, sl = c & 7, v = sl ^ (rp & 7);
    const int srow = rp * 2 + (v >> 2);
    pS[i] = A + (size_t)(row0 + srow) * INTER + (v & 3) * 8;
    dL[i] = (i * 256 + (tid & ~63)) * 16;
  }
#pragma unroll
  for (int i = 0; i < 3; ++i) {                 // B rows 0..191 (768 chunks)
    const int c = i * 256 + tid;
    const int rp = c >> 3, sl = c & 7, v = sl ^ (rp & 7);
    const int srow = rp * 2 + (v >> 2);         // 0..191
    pS[2 + i] = B + (size_t)(col0 + srow) * INTER + (v & 3) * 8;
    dL[2 + i] = 8192 + (i * 256 + (tid & ~63)) * 16;
  }

#define G2_STAGE(T, sb)                                                       \
  do {                                                                        \
    const int kk_ = (T) * BK;                                                 \
    _Pragma("unroll") for (int i_ = 0; i_ < 5; ++i_)                          \
      GLD16(pS[i_] + kk_, (sb) + dL[i_]);                                     \
  } while (0)

  int rdA[4], rdB[6];
#pragma unroll
  for (int m = 0; m < 4; ++m) rdA[m] = swz(wm * 64 + m * 16 + l15, l4);
#pragma unroll
  for (int n = 0; n < 6; ++n) rdB[n] = 8192 + swz(wn * 96 + n * 16 + l15, l4);

  f32x4 acc[4][6];
#pragma unroll
  for (int m = 0; m < 4; ++m)
#pragma unroll
    for (int n = 0; n < 6; ++n) acc[m][n] = (f32x4){0.f, 0.f, 0.f, 0.f};

  G2_STAGE(0, sm);
  G2_STAGE(1, sm + 20480);
  G2_STAGE(2, sm + 40960);
  VMCNT(10);
  BARRIER();

#pragma unroll 1
  for (int t = 0; t < NT; ++t) {
    char* sa = sm + (t & 3) * 20480;
    char* ss = sm + ((t + 3) & 3) * 20480;

    bf16x8 af[4], bfr[6];
#pragma unroll
    for (int m = 0; m < 4; ++m) af[m] = *(const bf16x8*)(sa + rdA[m]);
#pragma unroll
    for (int n = 0; n < 6; ++n) bfr[n] = *(const bf16x8*)(sa + rdB[n]);
    if (t + 3 < NT) G2_STAGE(t + 3, ss);
    __builtin_amdgcn_s_setprio(1);
#pragma unroll
    for (int m = 0; m < 4; ++m)
#pragma unroll
      for (int n = 0; n < 6; ++n)
        acc[m][n] = __builtin_amdgcn_mfma_f32_16x16x32_bf16(af[m], bfr[n], acc[m][n], 0, 0, 0);
    __builtin_amdgcn_s_setprio(0);
    if (t < NT - 3)       { VMCNT(10); }
    else if (t == NT - 3) { VMCNT(5); }
    else if (t == NT - 2) { VMCNT(0); }
    BARRIER();
  }

#pragma unroll
  for (int n = 0; n < 6; ++n) {
    const int col = col0 + wn * 96 + n * 16 + l15;
    const float bb = bias[col];
#pragma unroll
    for (int m = 0; m < 4; ++m) {
      const int r = row0 + wm * 64 + m * 16 + l4 * 4;
#pragma unroll
      for (int j = 0; j < 4; ++j)
        out[(size_t)(r + j) * HID + col] = acc[m][n][j] + bb;
    }
  }
#undef G2_STAGE
}

// ---------------------------------------------------------------------------
extern "C" void kernel_launch(void* const* d_in, const int* in_sizes, int n_in,
                              void* d_out, int out_size, void* d_ws, size_t ws_size,
                              hipStream_t stream) {
  (void)in_sizes; (void)n_in; (void)out_size; (void)ws_size;

  const float* hs  = (const float*)d_in[0];  // (4096, 2880)
  // d_in[1] router_w, d_in[2] router_b: unused — sum(softmax(topk)) == 1.
  const float* guw = (const float*)d_in[3];  // (5760, 2880)
  const float* gub = (const float*)d_in[4];  // (5760,)
  const float* dww = (const float*)d_in[5];  // (2880, 2880)
  const float* dwb = (const float*)d_in[6];  // (2880,)
  float* out = (float*)d_out;                // (4096, 2880)

  constexpr size_t n_hs  = (size_t)SEQ * HID;
  constexpr size_t n_guw = (size_t)(2 * INTER) * HID;
  constexpr size_t n_dww = (size_t)HID * INTER;

  bf16_t* ws   = (bf16_t*)d_ws;
  bf16_t* hsb  = ws;
  bf16_t* guwb = hsb + n_hs;
  bf16_t* dwwb = guwb + n_guw;
  bf16_t* xb   = dwwb + n_dww;  // (4096, 2880) bf16

  const size_t total4 = (n_hs + n_guw + n_dww) / 4;
  const int cgrid = (int)((total4 + 255) / 256);
  convert3<<<cgrid, 256, 0, stream>>>(hs, guw, dww, ws);

  gemm1<<<960, 256, 0, stream>>>(hsb, guwb, gub, xb);   // 32 x 30 tiles
  gemm2<<<480, 256, 0, stream>>>(xb, dwwb, dwb, out);   // 32 x 15 tiles
}